// Round 1
// baseline (306.431 us; speedup 1.0000x reference)
//
#include <hip/hip_runtime.h>

// Problem constants
#define BB 8
#define TT 1024
#define NH 8
#define HD 64
#define QT 64    // q rows per attention block (R13: halved, 2-wave blocks)

typedef unsigned short u16;
typedef __attribute__((ext_vector_type(8))) short bf16x8;
typedef __attribute__((ext_vector_type(16))) float f32x16;

__device__ __forceinline__ float bf2f(u16 s) {
    union { unsigned u; float f; } v; v.u = ((unsigned)s) << 16; return v.f;
}
__device__ __forceinline__ u16 f2bf(float f) {
    union { float f; unsigned u; } v; v.f = f;
    unsigned r = (v.u + 0x7FFFu + ((v.u >> 16) & 1u)) >> 16;
    return (u16)r;
}
__device__ __forceinline__ float bperm(int byte_idx, float v) {
    union { float f; int i; } a; a.f = v;
    union { int i; float f; } b;
    b.i = __builtin_amdgcn_ds_bpermute(byte_idx, a.i);
    return b.f;
}

#define MFMA(a, b, c) __builtin_amdgcn_mfma_f32_32x32x16_bf16((a), (b), (c), 0, 0, 0)

// ---------------------------------------------------------------------------
// Flat fp32 -> bf16 for x (4,194,304 elems) and rel_emb (65,600 elems).
// ---------------------------------------------------------------------------
#define NX4 1048576   // x float4 chunks
#define NR4 16400     // rel float4 chunks
__global__ void cvt_misc(const float* __restrict__ x, const float* __restrict__ rel,
                         u16* __restrict__ xb, u16* __restrict__ relb)
{
    size_t i = (size_t)blockIdx.x * 256 + threadIdx.x;
    const float* src; u16* dst;
    if (i < NX4) { src = x; dst = xb; }
    else {
        i -= NX4;
        if (i >= NR4) return;
        src = rel; dst = relb;
    }
    float4 f = *(const float4*)(src + i * 4);
    ushort4 o;
    o.x = f2bf(f.x); o.y = f2bf(f.y); o.z = f2bf(f.z); o.w = f2bf(f.w);
    *(ushort4*)(dst + i * 4) = o;
}

// ---------------------------------------------------------------------------
// Transpose W [512, N] fp32 -> W^T [N, 512] bf16 (Wq, Wkv, Wout in one grid).
// WqT and WkvT are laid out contiguously (WT_all[1536][512]).
// ---------------------------------------------------------------------------
__global__ __launch_bounds__(256) void cvt_wT(
    const float* __restrict__ Wq, const float* __restrict__ Wkv,
    const float* __restrict__ Wout,
    u16* __restrict__ WqT, u16* __restrict__ WkvT, u16* __restrict__ WoutT)
{
    __shared__ float tile[64][65];
    int bid = blockIdx.x;
    const float* W; u16* Wt; int N, kt, ct;
    if (bid < 64)       { W = Wq;   Wt = WqT;   N = 512;  kt = (bid >> 3) * 64; ct = (bid & 7) * 64; }
    else if (bid < 192) { bid -= 64;  W = Wkv;  Wt = WkvT; N = 1024; kt = (bid >> 4) * 64; ct = (bid & 15) * 64; }
    else                { bid -= 192; W = Wout; Wt = WoutT; N = 512;  kt = (bid >> 3) * 64; ct = (bid & 7) * 64; }

    const int tid = threadIdx.x;
#pragma unroll
    for (int i = 0; i < 16; i++) {
        int e = tid + i * 256;
        int r = e >> 6, c = e & 63;
        tile[r][c] = W[(size_t)(kt + r) * N + ct + c];
    }
    __syncthreads();
#pragma unroll
    for (int i = 0; i < 16; i++) {
        int e = tid + i * 256;
        int rr = e >> 6, cc = e & 63;   // output row = original col
        Wt[(size_t)(ct + rr) * 512 + kt + cc] = f2bf(tile[cc][rr]);
    }
}

// ---------------------------------------------------------------------------
// Fused qkv projection (bf16 MFMA, zero LDS), 64x64 per wave (proven R9).
// Block = 4 waves in 2x2 -> 128x128 tile. Grid (64, 12). MFMA:VMEM = 1:1.
// B given transposed: WT_all[1536][512]. c<512: q scaled 0.125 -> [b,h,t,d];
// 512..1024: k -> [b,h,t,d]; 1024..1536: v TRANSPOSED -> [b,h,d,t].
// ---------------------------------------------------------------------------
__global__ __launch_bounds__(256) void gemm_qkv(
    const u16* __restrict__ A, const u16* __restrict__ Bt,
    const float* __restrict__ bq, const float* __restrict__ bkv,
    u16* __restrict__ oq, u16* __restrict__ ok, u16* __restrict__ ov)
{
    const int tid = threadIdx.x;
    const int lane = tid & 63, w = tid >> 6;
    const int l31 = lane & 31, lh = lane >> 5;
    const int wr = w & 1, wc = w >> 1;
    const int row0 = blockIdx.x * 128 + 64 * wr;
    const int c0g  = blockIdx.y * 128 + 64 * wc;

    const u16* ap0 = A  + (size_t)(row0 + l31) * 512 + 8 * lh;
    const u16* ap1 = ap0 + (size_t)32 * 512;
    const u16* bp0 = Bt + (size_t)(c0g + l31) * 512 + 8 * lh;
    const u16* bp1 = bp0 + (size_t)32 * 512;

    f32x16 acc[2][2];
#pragma unroll
    for (int i = 0; i < 2; i++)
#pragma unroll
        for (int j = 0; j < 2; j++)
#pragma unroll
            for (int e = 0; e < 16; e++) acc[i][j][e] = 0.f;

#pragma unroll 4
    for (int ks = 0; ks < 32; ks++) {
        bf16x8 a0 = *(const bf16x8*)(ap0 + 16 * ks);
        bf16x8 a1 = *(const bf16x8*)(ap1 + 16 * ks);
        bf16x8 b0 = *(const bf16x8*)(bp0 + 16 * ks);
        bf16x8 b1 = *(const bf16x8*)(bp1 + 16 * ks);
        acc[0][0] = MFMA(a0, b0, acc[0][0]);
        acc[0][1] = MFMA(a0, b1, acc[0][1]);
        acc[1][0] = MFMA(a1, b0, acc[1][0]);
        acc[1][1] = MFMA(a1, b1, acc[1][1]);
    }

    const int rbase = 4 * lh;
#pragma unroll
    for (int ri = 0; ri < 2; ri++) {
#pragma unroll
        for (int ci = 0; ci < 2; ci++) {
            const int r0 = row0 + 32 * ri;
            const int gc = c0g + 32 * ci + l31;
            if (gc < 512) {            // q (scaled)
                const float bv = bq[gc];
                const int h = gc >> 6, d = gc & 63;
#pragma unroll
                for (int rg = 0; rg < 16; rg++) {
                    int gr = r0 + (rg & 3) + 8 * (rg >> 2) + rbase;
                    int b = gr >> 10, t = gr & 1023;
                    oq[(((size_t)b * NH + h) * TT + t) * HD + d] =
                        f2bf((acc[ri][ci][rg] + bv) * 0.125f);
                }
            } else if (gc < 1024) {    // k
                const float bv = bkv[gc - 512];
                const int h = (gc - 512) >> 6, d = gc & 63;
#pragma unroll
                for (int rg = 0; rg < 16; rg++) {
                    int gr = r0 + (rg & 3) + 8 * (rg >> 2) + rbase;
                    int b = gr >> 10, t = gr & 1023;
                    ok[(((size_t)b * NH + h) * TT + t) * HD + d] =
                        f2bf(acc[ri][ci][rg] + bv);
                }
            } else {                   // v, transposed [b,h,d,t]
                const float bv = bkv[gc - 512];
                const int vcol = gc - 1024;
                const int h = vcol >> 6, d = vcol & 63;
                const int b = r0 >> 10;
                const int t0 = (r0 & 1023) + rbase;
                size_t base = (((size_t)b * NH + h) * HD + d) * TT;
#pragma unroll
                for (int g = 0; g < 4; g++) {
                    ushort4 p;
                    p.x = f2bf(acc[ri][ci][4 * g + 0] + bv);
                    p.y = f2bf(acc[ri][ci][4 * g + 1] + bv);
                    p.z = f2bf(acc[ri][ci][4 * g + 2] + bv);
                    p.w = f2bf(acc[ri][ci][4 * g + 3] + bv);
                    *(ushort4*)&ov[base + t0 + 8 * g] = p;
                }
            }
        }
    }
}

// ---------------------------------------------------------------------------
// Out projection: out = a[8192,512] @ Wout + bout, fp32 result.
// Wave = 32 rows x 64 cols (2 accs). Grid (64, 8) = 512 blocks.
// ---------------------------------------------------------------------------
__global__ __launch_bounds__(256) void gemm_out(
    const u16* __restrict__ A, const u16* __restrict__ Bt,
    const float* __restrict__ bias, float* __restrict__ of)
{
    const int tid = threadIdx.x;
    const int lane = tid & 63, w = tid >> 6;
    const int l31 = lane & 31, lh = lane >> 5;
    const int row0 = blockIdx.x * 128 + 32 * w;
    const int c0 = blockIdx.y * 64;

    const u16* ap  = A  + (size_t)(row0 + l31) * 512 + 8 * lh;
    const u16* bp0 = Bt + (size_t)(c0 + l31) * 512 + 8 * lh;
    const u16* bp1 = bp0 + (size_t)32 * 512;

    f32x16 acc0, acc1;
#pragma unroll
    for (int i = 0; i < 16; i++) { acc0[i] = 0.f; acc1[i] = 0.f; }

#pragma unroll 4
    for (int ks = 0; ks < 32; ks++) {
        bf16x8 a  = *(const bf16x8*)(ap  + 16 * ks);
        bf16x8 b0 = *(const bf16x8*)(bp0 + 16 * ks);
        bf16x8 b1 = *(const bf16x8*)(bp1 + 16 * ks);
        acc0 = MFMA(a, b0, acc0);
        acc1 = MFMA(a, b1, acc1);
    }

    const int rbase = 4 * lh;
    const float bv0 = bias[c0 + l31];
    const float bv1 = bias[c0 + 32 + l31];
#pragma unroll
    for (int rg = 0; rg < 16; rg++) {
        int gr = row0 + (rg & 3) + 8 * (rg >> 2) + rbase;
        of[(size_t)gr * 512 + c0 + l31]      = acc0[rg] + bv0;
        of[(size_t)gr * 512 + c0 + 32 + l31] = acc1[rg] + bv1;
    }
}

// ---------------------------------------------------------------------------
// MFMA flash attention, rel-pos skew via ds_bpermute, barrier-free.
// R13 (occupancy): counters showed latency-bound (MfmaUtil 9.8, VALUBusy 24.5,
// Occupancy 10.8 -> 2 waves/SIMD, ~65% stall). Trade R12's 80-VGPR cross-tile
// ILP prefetch back for TLP:
//   - 128-thread blocks (2 waves), grid (64, 16) = 2048 blocks = 8/CU avail.
//   - __launch_bounds__(128, 3): >=3 waves/SIMD guaranteed (VGPR <= ~168).
//   - per-tile phase order G -> S -> softmax -> PV with staged issue:
//       rel frags double-buffered through the 3 G sub-tiles; K issued under
//       gt1/gt2 skew VALU (~500 cyc cover); V issued under exp+pack as before.
//     Skew ASSIGNS S (gt0 writes S1, gt1 writes S0) and QK MFMA accumulates
//     on top via its C operand -> no S zero-init, shorter S liveness.
// XCD clustering preserved: linear block id = bh + 64*by -> id%8 = bh%8.
// LDS: per-wave 32x104 u16 P buffer, 13.3 KB/block (6 blocks/CU = 80 KB).
// Spill tripwire: WRITE_SIZE must stay 8192 KB (R9 lesson).
// ---------------------------------------------------------------------------
__global__ __launch_bounds__(128, 3) void attn_mfma(
    const u16* __restrict__ q_ws, const u16* __restrict__ k_ws,
    const u16* __restrict__ v_ws, const u16* __restrict__ relb,
    u16* __restrict__ attn_out)
{
    __shared__ __align__(16) u16 GPs[2][32 * 104];   // per-wave P tile

    const int tid  = threadIdx.x;
    const int lane = tid & 63;
    const int w    = tid >> 6;          // 0..1
    const int l31  = lane & 31;
    const int lh   = lane >> 5;
    const int bh   = blockIdx.x;
    const int n0   = blockIdx.y * QT;   // 64-row q tile per block

    // Q A-fragments (rows n0+32w+l31), held in registers for all 16 m-tiles
    bf16x8 a_q[4];
    {
        const u16* qp = q_ws + (((size_t)bh * TT) + n0 + 32 * w + l31) * HD + 8 * lh;
#pragma unroll
        for (int ks = 0; ks < 4; ks++)
            a_q[ks] = *(const bf16x8*)(qp + 16 * ks);
    }

    f32x16 O0, O1;
    float li[16];
#pragma unroll
    for (int i = 0; i < 16; i++) { O0[i] = 0.f; O1[i] = 0.f; li[i] = 0.f; }

    u16* Gw = GPs[w];
    const int rbase = 4 * lh;
    const u16* kbase = k_ws + (size_t)bh * TT * HD;
    const u16* vbase = v_ws + (size_t)bh * HD * TT;
    const int pbb = n0 + 449 + 32 * w;  // rel-pos base for m0 = 0

    for (int mt = 0; mt < 16; mt++) {
        const int m0 = mt * 64;
        const int pb = pbb - m0;

        f32x16 S0, S1;

        // ---- rel frag loads for gt0/gt1 (double-buffered through G phase)
        bf16x8 rfA[4], rfB[4];
        {
            int p0 = pb + l31;       p0 = p0 < 0 ? 0 : (p0 > 1024 ? 1024 : p0);
            int p1 = pb + 32 + l31;  p1 = p1 < 0 ? 0 : (p1 > 1024 ? 1024 : p1);
            const u16* rb0 = relb + (size_t)p0 * HD;
            const u16* rb1 = relb + (size_t)p1 * HD;
#pragma unroll
            for (int ks = 0; ks < 4; ks++) {
                rfA[ks] = *(const bf16x8*)(rb0 + 16 * ks + 8 * lh);
                rfB[ks] = *(const bf16x8*)(rb1 + 16 * ks + 8 * lh);
            }
        }

        // ---- G gt=0: assigns S1 (no zero-init needed)
        {
            f32x16 g;
#pragma unroll
            for (int i = 0; i < 16; i++) g[i] = 0.f;
#pragma unroll
            for (int ks = 0; ks < 4; ks++) g = MFMA(a_q[ks], rfA[ks], g);
#pragma unroll
            for (int rg = 0; rg < 16; rg++) {
                int r = (rg & 3) + 8 * (rg >> 2) + rbase;
                int bidx = (((lh << 5) | ((r - l31 + 31) & 31))) << 2;
                float v = bperm(bidx, g[rg]);
                S1[rg] = (r > l31) ? 0.f : v;
            }
        }

        // ---- rel frag load for gt2 (reuse rfA)
        {
            int p2 = pb + 64 + l31;  p2 = p2 < 0 ? 0 : (p2 > 1024 ? 1024 : p2);
            const u16* rb2 = relb + (size_t)p2 * HD;
#pragma unroll
            for (int ks = 0; ks < 4; ks++)
                rfA[ks] = *(const bf16x8*)(rb2 + 16 * ks + 8 * lh);
        }

        // ---- G gt=1: assigns S0, accumulates S1
        {
            f32x16 g;
#pragma unroll
            for (int i = 0; i < 16; i++) g[i] = 0.f;
#pragma unroll
            for (int ks = 0; ks < 4; ks++) g = MFMA(a_q[ks], rfB[ks], g);
#pragma unroll
            for (int rg = 0; rg < 16; rg++) {
                int r = (rg & 3) + 8 * (rg >> 2) + rbase;
                int bidx = (((lh << 5) | ((r - l31 + 31) & 31))) << 2;
                float v = bperm(bidx, g[rg]);
                bool hi = r > l31;
                S0[rg] = hi ? 0.f : v;
                S1[rg] += hi ? v : 0.f;
            }
        }

        // ---- issue K loads; latency covered by gt2 MFMA + skew (~500 cyc)
        bf16x8 kf[8];
        {
            const u16* kb = kbase + (size_t)m0 * HD;
#pragma unroll
            for (int ks = 0; ks < 4; ks++) {
                const int doff = 16 * ks + 8 * lh;
                kf[2 * ks]     = *(const bf16x8*)(kb + (size_t)l31 * HD + doff);
                kf[2 * ks + 1] = *(const bf16x8*)(kb + (size_t)(l31 + 32) * HD + doff);
            }
        }

        // ---- G gt=2: accumulates S0
        {
            f32x16 g;
#pragma unroll
            for (int i = 0; i < 16; i++) g[i] = 0.f;
#pragma unroll
            for (int ks = 0; ks < 4; ks++) g = MFMA(a_q[ks], rfA[ks], g);
#pragma unroll
            for (int rg = 0; rg < 16; rg++) {
                int r = (rg & 3) + 8 * (rg >> 2) + rbase;
                int bidx = (((lh << 5) | ((r - l31 + 31) & 31))) << 2;
                float v = bperm(bidx, g[rg]);
                S0[rg] += (r > l31) ? v : 0.f;
            }
        }

        // ---- S += Q K^T (MFMA C-operand accumulates onto the skew)
#pragma unroll
        for (int ks = 0; ks < 4; ks++) {
            S0 = MFMA(a_q[ks], kf[2 * ks], S0);
            S1 = MFMA(a_q[ks], kf[2 * ks + 1], S1);
        }

        // ---- issue V loads; latency covered by exp + pack
        bf16x8 vf[8];
        {
            const u16* vb = vbase + m0;
#pragma unroll
            for (int ms = 0; ms < 4; ms++) {
                const int mg = 2 * ms + lh;
                vf[2 * ms]     = *(const bf16x8*)(vb + (size_t)l31 * TT + mg * 8);
                vf[2 * ms + 1] = *(const bf16x8*)(vb + (size_t)(l31 + 32) * TT + mg * 8);
            }
        }

        // ---- streaming softmax + P pack
#pragma unroll
        for (int rg = 0; rg < 16; rg++) {
            float e0 = __expf(S0[rg]);
            float e1 = __expf(S1[rg]);
            S0[rg] = e0; S1[rg] = e1;
            li[rg] += e0 + e1;
        }
#pragma unroll
        for (int rg = 0; rg < 16; rg++) {
            int r = (rg & 3) + 8 * (rg >> 2) + rbase;
            int ca = l31, cb = l31 + 32;
            Gw[r * 104 + (((ca >> 3) ^ (r & 7)) * 8) + (ca & 7)] = f2bf(S0[rg]);
            Gw[r * 104 + (((cb >> 3) ^ (r & 7)) * 8) + (cb & 7)] = f2bf(S1[rg]);
        }

        // ---- O += P V (waits vf only)
#pragma unroll
        for (int ms = 0; ms < 4; ms++) {
            const int mg = 2 * ms + lh;
            bf16x8 a_p = *(const bf16x8*)&Gw[l31 * 104 + ((mg ^ (l31 & 7)) * 8)];
            O0 = MFMA(a_p, vf[2 * ms], O0);
            O1 = MFMA(a_p, vf[2 * ms + 1], O1);
        }
    }

    // ---- epilogue: reduce li across the 32 lanes holding each row
#pragma unroll
    for (int rg = 0; rg < 16; rg++) {
        float rs = li[rg];
        rs += __shfl_xor(rs, 1);
        rs += __shfl_xor(rs, 2);
        rs += __shfl_xor(rs, 4);
        rs += __shfl_xor(rs, 8);
        rs += __shfl_xor(rs, 16);
        li[rg] = 1.0f / rs;
    }

    // write bf16 [b, t, h*64 + d]
    const int b = bh >> 3, h = bh & 7;
    u16* ob = attn_out + ((size_t)b * TT + n0 + 32 * w) * 512 + h * 64;
#pragma unroll
    for (int rg = 0; rg < 16; rg++) {
        int r = (rg & 3) + 8 * (rg >> 2) + rbase;
        ob[(size_t)r * 512 + l31]      = f2bf(O0[rg] * li[rg]);
        ob[(size_t)r * 512 + l31 + 32] = f2bf(O1[rg] * li[rg]);
    }
}

// ---------------------------------------------------------------------------
// Workspace layout (43 MB total — inside the PROVEN 44 MB envelope).
//   [ 0, 8)  q_wsb
//   [ 8,16)  k_wsb
//   [16,24)  v_wsb
//   [24,32)  x_bf (dead after gemm_qkv)
//   [32,40)  a_wsb (bf16 [b,t,512], written directly by attn)
//   [40,40.5) relb
//   [41,42.5) WT_all    [42.5,43) WoutT
// ---------------------------------------------------------------------------
extern "C" void kernel_launch(void* const* d_in, const int* in_sizes, int n_in,
                              void* d_out, int out_size, void* d_ws, size_t ws_size,
                              hipStream_t stream)
{
    const float* x    = (const float*)d_in[0];
    const float* Wq   = (const float*)d_in[1];
    const float* bq   = (const float*)d_in[2];
    const float* Wkv  = (const float*)d_in[3];
    const float* bkv  = (const float*)d_in[4];
    const float* Wout = (const float*)d_in[5];
    const float* bout = (const float*)d_in[6];
    const float* rel  = (const float*)d_in[7];
    float* out = (float*)d_out;

    char* ws = (char*)d_ws;
    const size_t MB = 1024 * 1024;
    u16*   q_wsb  = (u16*)(ws);                           // 8 MB [b,h,t,d]
    u16*   k_wsb  = (u16*)(ws + 8 * MB);                  // 8 MB [b,h,t,d]
    u16*   v_wsb  = (u16*)(ws + 16 * MB);                 // 8 MB [b,h,d,t]
    u16*   x_bf   = (u16*)(ws + 24 * MB);                 // 8 MB [8192,512]
    u16*   a_wsb  = (u16*)(ws + 32 * MB);                 // 8 MB [b,t,512]
    u16*   relb   = (u16*)(ws + 40 * MB);                 // 128 KB
    u16*   WT_all = (u16*)(ws + 41 * MB);                 // 1.5 MB [1536,512]
    u16*   WoutT  = (u16*)(ws + 42 * MB + 512 * 1024);    // 512 KB [512,512]

    // A: dtype conversions
    cvt_misc<<<(NX4 + NR4 + 255) / 256, 256, 0, stream>>>(x, rel, x_bf, relb);
    cvt_wT<<<256, 256, 0, stream>>>(Wq, Wkv, Wout, WT_all, WT_all + 512 * 512, WoutT);

    // B: fused qkv projection, 64x64/wave (768 blocks = 3/CU)
    gemm_qkv<<<dim3(64, 12), 256, 0, stream>>>(
        x_bf, WT_all, bq, bkv, q_wsb, k_wsb, v_wsb);

    // C: attention, XCD-clustered, bpermute skew, 2-wave blocks for occupancy
    attn_mfma<<<dim3(64, 16), 128, 0, stream>>>(
        q_wsb, k_wsb, v_wsb, relb, a_wsb);

    // D: out projection, 32x64/wave (512 blocks = 2/CU)
    gemm_out<<<dim3(64, 8), 256, 0, stream>>>(a_wsb, WoutT, bout, out);
}